// Round 1
// baseline (239.792 us; speedup 1.0000x reference)
//
#include <hip/hip_runtime.h>
#include <stdint.h>

typedef __attribute__((ext_vector_type(8))) short bf16x8;
typedef __attribute__((ext_vector_type(4))) float f32x4;

#define MFMA_16x16x32(a, b, c) __builtin_amdgcn_mfma_f32_16x16x32_bf16((a), (b), (c), 0, 0, 0)

__device__ __forceinline__ short f2bf(float f) {
  union { float f; uint32_t u; } x;
  x.f = f;
  uint32_t r = x.u + 0x7fffu + ((x.u >> 16) & 1u);
  return (short)(r >> 16);
}

__device__ __forceinline__ void gload_lds16(const short* g, short* l) {
  __builtin_amdgcn_global_load_lds(
      (const __attribute__((address_space(1))) void*)g,
      (__attribute__((address_space(3))) void*)l, 16, 0, 0);
}

// ---------------- cast f32 -> bf16, 8 elems/thread ----------------
__global__ __launch_bounds__(256) void cast_f32_bf16(const float* __restrict__ src,
                                                     short* __restrict__ dst, int n8) {
  int i = blockIdx.x * 256 + threadIdx.x;
  if (i >= n8) return;
  const float4* s = (const float4*)src;
  float4 v0 = s[i * 2 + 0];
  float4 v1 = s[i * 2 + 1];
  bf16x8 o;
  o[0] = f2bf(v0.x); o[1] = f2bf(v0.y); o[2] = f2bf(v0.z); o[3] = f2bf(v0.w);
  o[4] = f2bf(v1.x); o[5] = f2bf(v1.y); o[6] = f2bf(v1.z); o[7] = f2bf(v1.w);
  *(bf16x8*)(dst + (size_t)i * 8) = o;
}

// ---------------- bf16 GEMM, C[m,n] = sum_k A[m,k]*B[n,k] ----------------
// A: [M,K] row-major bf16, B: [N,K] row-major bf16 (i.e. B^T input form).
// 128x128 tile, BK=64, 256 threads (4 waves, 2x2 of 64x64 per wave).
template <int OUT_BF16>
__global__ __launch_bounds__(256) void gemm_bt(const short* __restrict__ A,
                                               const short* __restrict__ B,
                                               void* __restrict__ Cp,
                                               int M, int N, int K) {
  __shared__ short As[128 * 64];
  __shared__ short Bs[128 * 64];
  const int tid = threadIdx.x;
  const int wave = tid >> 6, lane = tid & 63;
  const int wr = wave >> 1, wc = wave & 1;
  const int row0 = blockIdx.y * 128, col0 = blockIdx.x * 128;
  const int lrow = lane & 15;   // operand row/col within 16
  const int kgrp = lane >> 4;   // k-group 0..3

  f32x4 acc[4][4] = {};

  for (int k0 = 0; k0 < K; k0 += 64) {
#pragma unroll
    for (int it = 0; it < 4; ++it) {
      int idx = it * 256 + tid;
      int r = idx >> 3, c8 = (idx & 7) * 8;
      gload_lds16(A + (row0 + r) * K + k0 + c8, As + (it * 256 + wave * 64) * 8);
      gload_lds16(B + (col0 + r) * K + k0 + c8, Bs + (it * 256 + wave * 64) * 8);
    }
    __syncthreads();
#pragma unroll
    for (int kk = 0; kk < 2; ++kk) {
      bf16x8 a[4], b[4];
#pragma unroll
      for (int m = 0; m < 4; ++m)
        a[m] = *(const bf16x8*)(As + (wr * 64 + m * 16 + lrow) * 64 + kk * 32 + kgrp * 8);
#pragma unroll
      for (int n = 0; n < 4; ++n)
        b[n] = *(const bf16x8*)(Bs + (wc * 64 + n * 16 + lrow) * 64 + kk * 32 + kgrp * 8);
#pragma unroll
      for (int m = 0; m < 4; ++m)
#pragma unroll
        for (int n = 0; n < 4; ++n)
          acc[m][n] = MFMA_16x16x32(a[m], b[n], acc[m][n]);
    }
    __syncthreads();
  }

#pragma unroll
  for (int m = 0; m < 4; ++m) {
    int rbase = row0 + wr * 64 + m * 16 + kgrp * 4;
#pragma unroll
    for (int n = 0; n < 4; ++n) {
      int col = col0 + wc * 64 + n * 16 + lrow;
#pragma unroll
      for (int j = 0; j < 4; ++j) {
        int off = (rbase + j) * N + col;
        if (OUT_BF16) ((short*)Cp)[off] = f2bf(acc[m][n][j]);
        else          ((float*)Cp)[off] = acc[m][n][j];
      }
    }
  }
}

// ---------------- V transpose: vt[b,h,d,t] <- qkv[b,t, 2C + h*64 + d] ----------------
__global__ __launch_bounds__(256) void transpose_v(const short* __restrict__ qkv,
                                                   short* __restrict__ vt) {
  const int T = 2048;
  __shared__ short sm[64][72];
  const int bh = blockIdx.y, h = bh & 15, b = bh >> 4;
  const int t0 = blockIdx.x * 64;
  const int tid = threadIdx.x;
#pragma unroll
  for (int p = 0; p < 2; ++p) {
    int idx = p * 256 + tid;
    int tl = idx >> 3, d0 = (idx & 7) * 8;
    bf16x8 v = *(const bf16x8*)(qkv + (b * T + t0 + tl) * 3072 + 2048 + h * 64 + d0);
    *(bf16x8*)(&sm[tl][d0]) = v;
  }
  __syncthreads();
#pragma unroll
  for (int p = 0; p < 2; ++p) {
    int idx = p * 256 + tid;
    int d = idx >> 3, ts0 = (idx & 7) * 8;
    bf16x8 o;
#pragma unroll
    for (int j = 0; j < 8; ++j) o[j] = sm[ts0 + j][d];
    *(bf16x8*)(vt + (bh * 64 + d) * T + t0 + ts0) = o;
  }
}

// ---------------- fused causal alibi attention with rational softmax ----------------
// grid: (T/64 q-tiles, B*H). 256 threads = 4 waves; wave w owns q rows [qb0+16w, +16).
// Streaming over K/V tiles of 64; no max tracking needed (rational softmax).
__global__ __launch_bounds__(256) void attn_kernel(const short* __restrict__ qkv,
                                                   const short* __restrict__ vt,
                                                   const float* __restrict__ slopes,
                                                   short* __restrict__ attn_out) {
  const int T = 2048, C = 1024, C3 = 3072;
  __shared__ short Klds[64 * 64];   // [s][d]
  __shared__ short Vlds[64 * 64];   // [d][s]  (from vt)
  __shared__ short Plds[4][16 * 64];// per-wave [q][s]
  __shared__ float denlds[64];

  const int tid = threadIdx.x, wave = tid >> 6, lane = tid & 63;
  const int bh = blockIdx.y, b = bh >> 4, h = bh & 15;
  const int qi = gridDim.x - 1 - blockIdx.x;  // heavy blocks dispatch first
  const int qb0 = qi * 64;
  const int lrow = lane & 15, kgrp = lane >> 4;
  const float slope = slopes[h];
  const float scale = 0.125f;  // 1/sqrt(64)

  // Q fragments, hoisted (B-operand of mfma(K,Q)): lane holds Q[qg][kk*32+kgrp*8 ..+7]
  const int qg = qb0 + wave * 16 + lrow;
  bf16x8 qf[2];
#pragma unroll
  for (int kk = 0; kk < 2; ++kk)
    qf[kk] = *(const bf16x8*)(qkv + (b * T + qg) * C3 + h * 64 + kk * 32 + kgrp * 8);

  f32x4 acc_o[4] = {};
  float den_p = 0.f;

  for (int kt = 0; kt <= qi; ++kt) {
    // stage K tile [64 s][64 d] and Vt tile [64 d][64 s]
#pragma unroll
    for (int p = 0; p < 2; ++p) {
      int idx = p * 256 + tid;
      int r = idx >> 3, c8 = (idx & 7) * 8;
      gload_lds16(qkv + (b * T + kt * 64 + r) * C3 + C + h * 64 + c8,
                  Klds + (p * 256 + wave * 64) * 8);
      gload_lds16(vt + (bh * 64 + r) * T + kt * 64 + c8,
                  Vlds + (p * 256 + wave * 64) * 8);
    }
    __syncthreads();

    // S^T = K * Q : D[row=s][col=q]; lane: q = lrow, s = r*16 + kgrp*4 + j
    f32x4 sacc[4] = {};
#pragma unroll
    for (int r = 0; r < 4; ++r) {
#pragma unroll
      for (int kk = 0; kk < 2; ++kk) {
        bf16x8 kf = *(const bf16x8*)(Klds + (r * 16 + lrow) * 64 + kk * 32 + kgrp * 8);
        sacc[r] = MFMA_16x16x32(kf, qf[kk], sacc[r]);
      }
    }

    // pointwise: scale + alibi + causal mask + rational numerator; write P[q][s] to LDS
#pragma unroll
    for (int r = 0; r < 4; ++r) {
      uint32_t pk0 = 0, pk1 = 0;
#pragma unroll
      for (int j = 0; j < 4; ++j) {
        int sg = kt * 64 + r * 16 + kgrp * 4 + j;
        float x = sacc[r][j] * scale - slope * (float)(qg - sg);
        x = (sg > qg) ? -10000.0f : x;
        float num = 0.5f * (1.0f + x * rsqrtf(1.0f + x * x));
        den_p += num;
        uint32_t bf = (uint32_t)(uint16_t)f2bf(num);
        if (j == 0) pk0 = bf;
        else if (j == 1) pk0 |= bf << 16;
        else if (j == 2) pk1 = bf;
        else pk1 |= bf << 16;
      }
      *(unsigned long long*)(Plds[wave] + lrow * 64 + r * 16 + kgrp * 4) =
          ((unsigned long long)pk1 << 32) | pk0;
    }
    asm volatile("s_waitcnt lgkmcnt(0)" ::: "memory");

    // PV: out[q][d] += P[q][s] * V[s][d]
#pragma unroll
    for (int kk = 0; kk < 2; ++kk) {
      bf16x8 pf = *(const bf16x8*)(Plds[wave] + lrow * 64 + kk * 32 + kgrp * 8);
#pragma unroll
      for (int n = 0; n < 4; ++n) {
        bf16x8 vf = *(const bf16x8*)(Vlds + (n * 16 + lrow) * 64 + kk * 32 + kgrp * 8);
        acc_o[n] = MFMA_16x16x32(pf, vf, acc_o[n]);
      }
    }
    __syncthreads();
  }

  // reduce den across the 4 k-groups holding the same q (= lane&15)
  float den = den_p + __shfl_xor(den_p, 16);
  den += __shfl_xor(den, 32);
  denlds[wave * 16 + lrow] = den;
  asm volatile("s_waitcnt lgkmcnt(0)" ::: "memory");

  // epilogue: out D-layout row=q=kgrp*4+j, col=d=n*16+lrow
#pragma unroll
  for (int n = 0; n < 4; ++n) {
    int d = h * 64 + n * 16 + lrow;
#pragma unroll
    for (int j = 0; j < 4; ++j) {
      int qrow = kgrp * 4 + j;
      float dv = denlds[wave * 16 + qrow] + 1e-6f;
      float val = acc_o[n][j] / dv;
      attn_out[(b * T + qb0 + wave * 16 + qrow) * C + h * 64 + n * 16 + lrow] = f2bf(val);
      (void)d;
    }
  }
}

// ---------------- launcher ----------------
extern "C" void kernel_launch(void* const* d_in, const int* in_sizes, int n_in,
                              void* d_out, int out_size, void* d_ws, size_t ws_size,
                              hipStream_t stream) {
  const float* x      = (const float*)d_in[0];
  const float* w_qkv  = (const float*)d_in[1];
  const float* w_out  = (const float*)d_in[2];
  const float* slopes = (const float*)d_in[3];

  const int B = 2, T = 2048, C = 1024;
  const int M = B * T;        // 4096
  const int N1 = 3 * C;       // 3072

  char* ws = (char*)d_ws;
  short* x_bf    = (short*)(ws);                      //  8,388,608 B
  short* wqkv_bf = (short*)(ws + 8388608);            //  6,291,456 B
  short* wout_bf = (short*)(ws + 14680064);           //  2,097,152 B
  short* qkv_bf  = (short*)(ws + 16777216);           // 25,165,824 B
  short* vt_bf   = (short*)(ws + 41943040);           //  8,388,608 B
  short* ao_bf   = (short*)(ws + 50331648);           //  8,388,608 B  (total 58,720,256)

  // casts
  cast_f32_bf16<<<(M * C / 8 + 255) / 256, 256, 0, stream>>>(x, x_bf, M * C / 8);
  cast_f32_bf16<<<(N1 * C / 8 + 255) / 256, 256, 0, stream>>>(w_qkv, wqkv_bf, N1 * C / 8);
  cast_f32_bf16<<<(C * C / 8 + 255) / 256, 256, 0, stream>>>(w_out, wout_bf, C * C / 8);

  // qkv = x @ w_qkv^T  -> bf16
  gemm_bt<1><<<dim3(N1 / 128, M / 128), 256, 0, stream>>>(x_bf, wqkv_bf, qkv_bf, M, N1, C);

  // vt[b,h,d,t]
  transpose_v<<<dim3(T / 64, 32), 256, 0, stream>>>(qkv_bf, vt_bf);

  // fused attention -> ao_bf [B,T,C]
  attn_kernel<<<dim3(T / 64, 32), 256, 0, stream>>>(qkv_bf, vt_bf, slopes, ao_bf);

  // out = attn @ w_out^T -> f32
  gemm_bt<0><<<dim3(C / 128, M / 128), 256, 0, stream>>>(ao_bf, wout_bf, (float*)d_out, M, C, C);
}

// Round 2
// 139.807 us; speedup vs baseline: 1.7152x; 1.7152x over previous
//
#include <hip/hip_runtime.h>
#include <stdint.h>

typedef __attribute__((ext_vector_type(8))) short bf16x8;
typedef __attribute__((ext_vector_type(4))) float f32x4;
typedef __attribute__((ext_vector_type(2))) unsigned int u32x2;

#define MFMA_16x16x32(a, b, c) __builtin_amdgcn_mfma_f32_16x16x32_bf16((a), (b), (c), 0, 0, 0)

__device__ __forceinline__ short f2bf(float f) {
  union { float f; uint32_t u; } x;
  x.f = f;
  uint32_t r = x.u + 0x7fffu + ((x.u >> 16) & 1u);
  return (short)(r >> 16);
}

__device__ __forceinline__ uint32_t cvt_pk_bf16(float lo, float hi) {
  uint32_t r;
  asm("v_cvt_pk_bf16_f32 %0, %1, %2" : "=v"(r) : "v"(lo), "v"(hi));
  return r;
}

__device__ __forceinline__ void gload_lds16(const short* g, short* l) {
  __builtin_amdgcn_global_load_lds(
      (const __attribute__((address_space(1))) void*)g,
      (__attribute__((address_space(3))) void*)l, 16, 0, 0);
}

// ---------------- cast f32 -> bf16, 8 elems/thread ----------------
__global__ __launch_bounds__(256) void cast_f32_bf16(const float* __restrict__ src,
                                                     short* __restrict__ dst, int n8) {
  int i = blockIdx.x * 256 + threadIdx.x;
  if (i >= n8) return;
  const float4* s = (const float4*)src;
  float4 v0 = s[i * 2 + 0];
  float4 v1 = s[i * 2 + 1];
  bf16x8 o;
  o[0] = f2bf(v0.x); o[1] = f2bf(v0.y); o[2] = f2bf(v0.z); o[3] = f2bf(v0.w);
  o[4] = f2bf(v1.x); o[5] = f2bf(v1.y); o[6] = f2bf(v1.z); o[7] = f2bf(v1.w);
  *(bf16x8*)(dst + (size_t)i * 8) = o;
}

// ---------------- bf16 GEMM, C[m,n] = sum_k A[m,k]*B[n,k] ----------------
template <int OUT_BF16>
__global__ __launch_bounds__(256) void gemm_bt(const short* __restrict__ A,
                                               const short* __restrict__ B,
                                               void* __restrict__ Cp,
                                               int M, int N, int K) {
  __shared__ short As[128 * 64];
  __shared__ short Bs[128 * 64];
  const int tid = threadIdx.x;
  const int wave = tid >> 6, lane = tid & 63;
  const int wr = wave >> 1, wc = wave & 1;
  const int row0 = blockIdx.y * 128, col0 = blockIdx.x * 128;
  const int lrow = lane & 15;
  const int kgrp = lane >> 4;

  f32x4 acc[4][4] = {};

  for (int k0 = 0; k0 < K; k0 += 64) {
#pragma unroll
    for (int it = 0; it < 4; ++it) {
      int idx = it * 256 + tid;
      int r = idx >> 3, c8 = (idx & 7) * 8;
      gload_lds16(A + (row0 + r) * K + k0 + c8, As + (it * 256 + wave * 64) * 8);
      gload_lds16(B + (col0 + r) * K + k0 + c8, Bs + (it * 256 + wave * 64) * 8);
    }
    __syncthreads();
#pragma unroll
    for (int kk = 0; kk < 2; ++kk) {
      bf16x8 a[4], b[4];
#pragma unroll
      for (int m = 0; m < 4; ++m)
        a[m] = *(const bf16x8*)(As + (wr * 64 + m * 16 + lrow) * 64 + kk * 32 + kgrp * 8);
#pragma unroll
      for (int n = 0; n < 4; ++n)
        b[n] = *(const bf16x8*)(Bs + (wc * 64 + n * 16 + lrow) * 64 + kk * 32 + kgrp * 8);
#pragma unroll
      for (int m = 0; m < 4; ++m)
#pragma unroll
        for (int n = 0; n < 4; ++n)
          acc[m][n] = MFMA_16x16x32(a[m], b[n], acc[m][n]);
    }
    __syncthreads();
  }

#pragma unroll
  for (int m = 0; m < 4; ++m) {
    int rbase = row0 + wr * 64 + m * 16 + kgrp * 4;
#pragma unroll
    for (int n = 0; n < 4; ++n) {
      int col = col0 + wc * 64 + n * 16 + lrow;
#pragma unroll
      for (int j = 0; j < 4; ++j) {
        int off = (rbase + j) * N + col;
        if (OUT_BF16) ((short*)Cp)[off] = f2bf(acc[m][n][j]);
        else          ((float*)Cp)[off] = acc[m][n][j];
      }
    }
  }
}

// ---------------- V transpose: vt[b,h,d,t] <- qkv[b,t, 2C + h*64 + d] ----------------
__global__ __launch_bounds__(256) void transpose_v(const short* __restrict__ qkv,
                                                   short* __restrict__ vt) {
  const int T = 2048;
  __shared__ short sm[64][72];
  const int bh = blockIdx.y, h = bh & 15, b = bh >> 4;
  const int t0 = blockIdx.x * 64;
  const int tid = threadIdx.x;
#pragma unroll
  for (int p = 0; p < 2; ++p) {
    int idx = p * 256 + tid;
    int tl = idx >> 3, d0 = (idx & 7) * 8;
    bf16x8 v = *(const bf16x8*)(qkv + (b * T + t0 + tl) * 3072 + 2048 + h * 64 + d0);
    *(bf16x8*)(&sm[tl][d0]) = v;
  }
  __syncthreads();
#pragma unroll
  for (int p = 0; p < 2; ++p) {
    int idx = p * 256 + tid;
    int d = idx >> 3, ts0 = (idx & 7) * 8;
    bf16x8 o;
#pragma unroll
    for (int j = 0; j < 8; ++j) o[j] = sm[ts0 + j][d];
    *(bf16x8*)(vt + (bh * 64 + d) * T + t0 + ts0) = o;
  }
}

// ---------------- fused attention ----------------
// One compute step for one q-tile against the staged K/V tile.
// All LDS fragment addresses XOR-swizzled: slot ^= (row & 7).
template <bool DIAG>
__device__ __forceinline__ void attn_step(
    const short* __restrict__ Kb, const short* __restrict__ Vb,
    short* __restrict__ Pw, const bf16x8 (&qf)[2], const float (&cbase)[4][4],
    float off, f32x4 (&acc)[4], float& den,
    int lrow, int kgrp, int l3, int dthr) {
  const float scale = 0.125f;
  f32x4 s[4];
#pragma unroll
  for (int r = 0; r < 4; ++r) {
    f32x4 z = {0.f, 0.f, 0.f, 0.f};
#pragma unroll
    for (int kk = 0; kk < 2; ++kk) {
      bf16x8 kf = *(const bf16x8*)(Kb + (r * 16 + lrow) * 64 + 8 * ((kk * 4 + kgrp) ^ l3));
      z = MFMA_16x16x32(kf, qf[kk], z);
    }
    s[r] = z;
  }
#pragma unroll
  for (int r = 0; r < 4; ++r) {
    float nm[4];
#pragma unroll
    for (int j = 0; j < 4; ++j) {
      float x = fmaf(s[r][j], scale, cbase[r][j] + off);
      if (DIAG) x = ((r * 16 + kgrp * 4 + j) > dthr) ? -10000.0f : x;
      float t = fmaf(x, x, 1.0f);
      float xr = x * __builtin_amdgcn_rsqf(t);
      float v = fmaf(xr, 0.5f, 0.5f);
      den += v;
      nm[j] = v;
    }
    u32x2 pk;
    pk[0] = cvt_pk_bf16(nm[0], nm[1]);
    pk[1] = cvt_pk_bf16(nm[2], nm[3]);
    *(u32x2*)(Pw + lrow * 64 + ((r * 16 + kgrp * 4) ^ (l3 * 8))) = pk;
  }
  asm volatile("s_waitcnt lgkmcnt(0)" ::: "memory");
#pragma unroll
  for (int kk = 0; kk < 2; ++kk) {
    bf16x8 pf = *(const bf16x8*)(Pw + lrow * 64 + 8 * ((kk * 4 + kgrp) ^ l3));
#pragma unroll
    for (int n = 0; n < 4; ++n) {
      bf16x8 vf = *(const bf16x8*)(Vb + (n * 16 + lrow) * 64 + 8 * ((kk * 4 + kgrp) ^ l3));
      acc[n] = MFMA_16x16x32(pf, vf, acc[n]);
    }
  }
}

// grid (16, B*H). Block bx handles q-tiles qiA=31-bx and qiB=bx (uniform 33 steps).
__global__ __launch_bounds__(256, 2) void attn_kernel(const short* __restrict__ qkv,
                                                      const short* __restrict__ vt,
                                                      const float* __restrict__ slopes,
                                                      short* __restrict__ attn_out) {
  const int T = 2048, C = 1024, C3 = 3072;
  __shared__ short Kl[2][4096];
  __shared__ short Vl[2][4096];
  __shared__ short Pl[4][2][1024];
  __shared__ float denl[4][16];

  const int tid = threadIdx.x, wave = tid >> 6, lane = tid & 63;
  const int bh = blockIdx.y, b = bh >> 4, h = bh & 15;
  const int bx = blockIdx.x;
  const int qiA = 31 - bx, qiB = bx;
  const int lrow = lane & 15, kgrp = lane >> 4, l3 = lrow & 7;
  const float slope = slopes[h];
  const int dthr = wave * 16 + lrow;

  // hoisted Q fragments for both q-tiles
  const int qgA = qiA * 64 + wave * 16 + lrow;
  const int qgB = qiB * 64 + wave * 16 + lrow;
  bf16x8 qfA[2], qfB[2];
#pragma unroll
  for (int kk = 0; kk < 2; ++kk) {
    qfA[kk] = *(const bf16x8*)(qkv + (b * T + qgA) * C3 + h * 64 + kk * 32 + kgrp * 8);
    qfB[kk] = *(const bf16x8*)(qkv + (b * T + qgB) * C3 + h * 64 + kk * 32 + kgrp * 8);
  }

  // alibi per-lane constants: cbase[r][j] = slope*((s-in-tile) - (q-in-tile))
  float cbase[4][4];
#pragma unroll
  for (int r = 0; r < 4; ++r)
#pragma unroll
    for (int j = 0; j < 4; ++j)
      cbase[r][j] = slope * (float)(r * 16 + kgrp * 4 + j - wave * 16 - lrow);

  f32x4 accA[4] = {}, accB[4] = {};
  float denA = 0.f, denB = 0.f;

  auto STAGE = [&](int bufi, int kt) {
#pragma unroll
    for (int p = 0; p < 2; ++p) {
      int idx = p * 256 + tid;
      int r = idx >> 3;
      int c8s = ((idx & 7) ^ (r & 7)) * 8;   // pre-swizzled global source column
      gload_lds16(qkv + (b * T + kt * 64 + r) * C3 + C + h * 64 + c8s,
                  &Kl[bufi][(p * 256 + wave * 64) * 8]);
      gload_lds16(vt + (bh * 64 + r) * T + kt * 64 + c8s,
                  &Vl[bufi][(p * 256 + wave * 64) * 8]);
    }
  };

  STAGE(0, 0);
  __syncthreads();
  int cur = 0;
  int kt = 0;
  const float s64 = slope * 64.0f;

  // phase 1: kt in [0, qiB) — both tiles, no diagonal
  for (; kt < qiB; ++kt) {
    STAGE(cur ^ 1, kt + 1);
    attn_step<false>(Kl[cur], Vl[cur], Pl[wave][0], qfA, cbase,
                     s64 * (float)(kt - qiA), accA, denA, lrow, kgrp, l3, dthr);
    attn_step<false>(Kl[cur], Vl[cur], Pl[wave][1], qfB, cbase,
                     s64 * (float)(kt - qiB), accB, denB, lrow, kgrp, l3, dthr);
    __syncthreads();
    cur ^= 1;
  }
  // kt == qiB (< qiA): A plain, B diagonal
  {
    STAGE(cur ^ 1, kt + 1);
    attn_step<false>(Kl[cur], Vl[cur], Pl[wave][0], qfA, cbase,
                     s64 * (float)(kt - qiA), accA, denA, lrow, kgrp, l3, dthr);
    attn_step<true>(Kl[cur], Vl[cur], Pl[wave][1], qfB, cbase,
                    0.0f, accB, denB, lrow, kgrp, l3, dthr);
    __syncthreads();
    cur ^= 1;
    ++kt;
  }
  // phase 3: kt in (qiB, qiA) — A only
  for (; kt < qiA; ++kt) {
    STAGE(cur ^ 1, kt + 1);
    attn_step<false>(Kl[cur], Vl[cur], Pl[wave][0], qfA, cbase,
                     s64 * (float)(kt - qiA), accA, denA, lrow, kgrp, l3, dthr);
    __syncthreads();
    cur ^= 1;
  }
  // kt == qiA: A diagonal, no prefetch, no barrier needed after
  attn_step<true>(Kl[cur], Vl[cur], Pl[wave][0], qfA, cbase,
                  0.0f, accA, denA, lrow, kgrp, l3, dthr);

  // epilogues
  {
    float d2 = denA + __shfl_xor(denA, 16);
    d2 += __shfl_xor(d2, 32);
    denl[wave][lrow] = d2;
    float rcpd[4];
#pragma unroll
    for (int j = 0; j < 4; ++j)
      rcpd[j] = __builtin_amdgcn_rcpf(denl[wave][kgrp * 4 + j] + 1e-6f);
#pragma unroll
    for (int n = 0; n < 4; ++n)
#pragma unroll
      for (int j = 0; j < 4; ++j) {
        int qrow = kgrp * 4 + j;
        attn_out[(b * T + qiA * 64 + wave * 16 + qrow) * C + h * 64 + n * 16 + lrow] =
            f2bf(accA[n][j] * rcpd[j]);
      }
  }
  {
    float d2 = denB + __shfl_xor(denB, 16);
    d2 += __shfl_xor(d2, 32);
    denl[wave][lrow] = d2;
    float rcpd[4];
#pragma unroll
    for (int j = 0; j < 4; ++j)
      rcpd[j] = __builtin_amdgcn_rcpf(denl[wave][kgrp * 4 + j] + 1e-6f);
#pragma unroll
    for (int n = 0; n < 4; ++n)
#pragma unroll
      for (int j = 0; j < 4; ++j) {
        int qrow = kgrp * 4 + j;
        attn_out[(b * T + qiB * 64 + wave * 16 + qrow) * C + h * 64 + n * 16 + lrow] =
            f2bf(accB[n][j] * rcpd[j]);
      }
  }
}

// ---------------- launcher ----------------
extern "C" void kernel_launch(void* const* d_in, const int* in_sizes, int n_in,
                              void* d_out, int out_size, void* d_ws, size_t ws_size,
                              hipStream_t stream) {
  const float* x      = (const float*)d_in[0];
  const float* w_qkv  = (const float*)d_in[1];
  const float* w_out  = (const float*)d_in[2];
  const float* slopes = (const float*)d_in[3];

  const int B = 2, T = 2048, C = 1024;
  const int M = B * T;        // 4096
  const int N1 = 3 * C;       // 3072

  char* ws = (char*)d_ws;
  short* x_bf    = (short*)(ws);
  short* wqkv_bf = (short*)(ws + 8388608);
  short* wout_bf = (short*)(ws + 14680064);
  short* qkv_bf  = (short*)(ws + 16777216);
  short* vt_bf   = (short*)(ws + 41943040);
  short* ao_bf   = (short*)(ws + 50331648);

  cast_f32_bf16<<<(M * C / 8 + 255) / 256, 256, 0, stream>>>(x, x_bf, M * C / 8);
  cast_f32_bf16<<<(N1 * C / 8 + 255) / 256, 256, 0, stream>>>(w_qkv, wqkv_bf, N1 * C / 8);
  cast_f32_bf16<<<(C * C / 8 + 255) / 256, 256, 0, stream>>>(w_out, wout_bf, C * C / 8);

  gemm_bt<1><<<dim3(N1 / 128, M / 128), 256, 0, stream>>>(x_bf, wqkv_bf, qkv_bf, M, N1, C);

  transpose_v<<<dim3(T / 64, 32), 256, 0, stream>>>(qkv_bf, vt_bf);

  attn_kernel<<<dim3(16, 32), 256, 0, stream>>>(qkv_bf, vt_bf, slopes, ao_bf);

  gemm_bt<0><<<dim3(C / 128, M / 128), 256, 0, stream>>>(ao_bf, wout_bf, (float*)d_out, M, C, C);
}

// Round 3
// 125.359 us; speedup vs baseline: 1.9128x; 1.1153x over previous
//
#include <hip/hip_runtime.h>
#include <stdint.h>

typedef __attribute__((ext_vector_type(8))) short bf16x8;
typedef __attribute__((ext_vector_type(4))) float f32x4;
typedef __attribute__((ext_vector_type(2))) unsigned int u32x2;

#define MFMA_16x16x32(a, b, c) __builtin_amdgcn_mfma_f32_16x16x32_bf16((a), (b), (c), 0, 0, 0)

__device__ __forceinline__ short f2bf(float f) {
  union { float f; uint32_t u; } x;
  x.f = f;
  uint32_t r = x.u + 0x7fffu + ((x.u >> 16) & 1u);
  return (short)(r >> 16);
}

__device__ __forceinline__ uint32_t cvt_pk_bf16(float lo, float hi) {
  uint32_t r;
  asm("v_cvt_pk_bf16_f32 %0, %1, %2" : "=v"(r) : "v"(lo), "v"(hi));
  return r;
}

__device__ __forceinline__ void gload_lds16(const short* g, short* l) {
  __builtin_amdgcn_global_load_lds(
      (const __attribute__((address_space(1))) void*)g,
      (__attribute__((address_space(3))) void*)l, 16, 0, 0);
}

// ---------------- cast f32 -> bf16, 8 elems/thread ----------------
__global__ __launch_bounds__(256) void cast_f32_bf16(const float* __restrict__ src,
                                                     short* __restrict__ dst, int n8) {
  int i = blockIdx.x * 256 + threadIdx.x;
  if (i >= n8) return;
  const float4* s = (const float4*)src;
  float4 v0 = s[i * 2 + 0];
  float4 v1 = s[i * 2 + 1];
  bf16x8 o;
  o[0] = f2bf(v0.x); o[1] = f2bf(v0.y); o[2] = f2bf(v0.z); o[3] = f2bf(v0.w);
  o[4] = f2bf(v1.x); o[5] = f2bf(v1.y); o[6] = f2bf(v1.z); o[7] = f2bf(v1.w);
  *(bf16x8*)(dst + (size_t)i * 8) = o;
}

// ---------------- 256x256 8-phase bf16 GEMM (C = A * B^T form) ----------------
// A:[M,K] bf16 row-major, B:[N,K] bf16 row-major. 512 threads = 8 waves (2Mx4N).
// BK=64, 2 K-tiles/iter, 8 phases/iter, counted vmcnt(4), XOR-swizzled LDS.
template <int OUT_BF16>
__global__ __launch_bounds__(512, 2) void gemm256(const short* __restrict__ A,
                                                  const short* __restrict__ B,
                                                  void* __restrict__ Cp,
                                                  int M, int N, int K, int ntN) {
  __shared__ short Al[2][2][128 * 64];   // [slot][half][row*64+col]
  __shared__ short Bl[2][2][128 * 64];

  const int tid = threadIdx.x;
  const int wv = tid >> 6, lane = tid & 63;
  const int wr = wv >> 2, wc = wv & 3;            // 2M x 4N waves
  const int lrow = lane & 15, kgrp = lane >> 4;
  const int l3 = lrow & 7;
  const int ck0 = ((kgrp ^ l3)) * 8;
  const int ck1 = ((kgrp ^ l3) ^ 4) * 8;

  // XCD-aware swizzle (nwg % 8 == 0 by construction)
  const int nwg = gridDim.x;
  const int orig = blockIdx.x;
  const int wg = (orig & 7) * (nwg >> 3) + (orig >> 3);
  const int by = wg / ntN, bx = wg % ntN;
  const int row0 = by * 256, col0 = bx * 256;

  // staging geometry: one half = 128 rows x 64 cols = 16KB = 2 issues of 512x16B
  const int r_ = tid >> 3;                        // 0..63 (row within 64-row group)
  const int cs_ = ((tid & 7) ^ (r_ & 7)) * 8;     // pre-swizzled source chunk (shorts)

  const int NT = K >> 6;          // 16 K-tiles
  const int NI = NT >> 1;         // 8 iterations
  const int NTm1 = NT - 1;

  auto stgA = [&](int slot, int h, int j, int kt) {
    gload_lds16(A + (size_t)(row0 + h * 128 + j * 64 + r_) * K + kt * 64 + cs_,
                &Al[slot][h][j * 4096 + wv * 512]);
  };
  auto stgB = [&](int slot, int h, int j, int kt) {
    gload_lds16(B + (size_t)(col0 + h * 128 + j * 64 + r_) * K + kt * 64 + cs_,
                &Bl[slot][h][j * 4096 + wv * 512]);
  };

  f32x4 acc[8][4] = {};

  const int boff = ((wc & 1) * 64 + lrow) * 64;   // B row-in-half * 64
  const int bh = wc >> 1;                          // B half

  // prologue: tile0 -> slot0 (B then A), B of tile1 -> slot1  => 12 in flight
  stgB(0, 0, 0, 0); stgB(0, 0, 1, 0); stgB(0, 1, 0, 0); stgB(0, 1, 1, 0);
  stgA(0, 0, 0, 0); stgA(0, 0, 1, 0); stgA(0, 1, 0, 0); stgA(0, 1, 1, 0);
  stgB(1, 0, 0, 1); stgB(1, 0, 1, 1); stgB(1, 1, 0, 1); stgB(1, 1, 1, 1);
  asm volatile("s_waitcnt vmcnt(4)" ::: "memory");   // tile0 fully landed
  __builtin_amdgcn_s_barrier();

  for (int i = 0; i < NI; ++i) {
    const int ktB1 = (2 * i + 1);                       // always valid
    const int ktP2 = (2 * i + 2 > NTm1) ? NTm1 : 2 * i + 2;  // clamped (dead-region re-stage)
    const int ktP3 = (2 * i + 3 > NTm1) ? NTm1 : 2 * i + 3;
#pragma unroll
    for (int s = 0; s < 2; ++s) {
      bf16x8 bfr[4][2];
#pragma unroll
      for (int q = 0; q < 4; ++q) {
        // --- ds reads for this phase ---
        if (q == 0) {
#pragma unroll
          for (int n = 0; n < 4; ++n) {
            bfr[n][0] = *(const bf16x8*)(&Bl[s][bh][boff + n * 1024 + ck0]);
            bfr[n][1] = *(const bf16x8*)(&Bl[s][bh][boff + n * 1024 + ck1]);
          }
        }
        bf16x8 afr[2][2];
#pragma unroll
        for (int mm = 0; mm < 2; ++mm) {
          const int m = q * 2 + mm;
          afr[mm][0] = *(const bf16x8*)(&Al[s][wr][lrow * 64 + m * 1024 + ck0]);
          afr[mm][1] = *(const bf16x8*)(&Al[s][wr][lrow * 64 + m * 1024 + ck1]);
        }
        // --- stage schedule (one half-tile per phase; dead-region targets only) ---
        if (s == 0) {
          if (q == 0) { stgA(1, 0, 0, ktB1); stgA(1, 0, 1, ktB1); stgA(1, 1, 0, ktB1); stgA(1, 1, 1, ktB1); }
          else if (q == 1) { stgB(0, 0, 0, ktP2); stgB(0, 0, 1, ktP2); }
          else if (q == 2) { stgB(0, 1, 0, ktP2); stgB(0, 1, 1, ktP2); }
        } else {
          if (q == 0) { stgA(0, 0, 0, ktP2); stgA(0, 0, 1, ktP2); stgA(0, 1, 0, ktP2); stgA(0, 1, 1, ktP2); }
          else if (q == 1) { stgB(1, 0, 0, ktP3); stgB(1, 0, 1, ktP3); }
          else if (q == 2) { stgB(1, 1, 0, ktP3); stgB(1, 1, 1, ktP3); }
        }
        __builtin_amdgcn_sched_barrier(0);
        __builtin_amdgcn_s_barrier();
        asm volatile("s_waitcnt lgkmcnt(0)" ::: "memory");
        __builtin_amdgcn_sched_barrier(0);
        __builtin_amdgcn_s_setprio(1);
#pragma unroll
        for (int mm = 0; mm < 2; ++mm)
#pragma unroll
          for (int n = 0; n < 4; ++n)
#pragma unroll
            for (int kk = 0; kk < 2; ++kk)
              acc[q * 2 + mm][n] = MFMA_16x16x32(afr[mm][kk], bfr[n][kk], acc[q * 2 + mm][n]);
        __builtin_amdgcn_s_setprio(0);
        __builtin_amdgcn_sched_barrier(0);
        if (q == 3) {
          // counted wait: 12 in flight -> 4; oldest 8 = next tile's 4 half-tiles
          asm volatile("s_waitcnt vmcnt(4)" ::: "memory");
        }
        __builtin_amdgcn_s_barrier();
      }
    }
  }

  asm volatile("s_waitcnt vmcnt(0)" ::: "memory");  // drain clamped re-stages

  // epilogue
#pragma unroll
  for (int m = 0; m < 8; ++m) {
    const int grow = row0 + wr * 128 + m * 16 + kgrp * 4;
#pragma unroll
    for (int n = 0; n < 4; ++n) {
      const int gcol = col0 + wc * 64 + n * 16 + lrow;
#pragma unroll
      for (int j = 0; j < 4; ++j) {
        const size_t off = (size_t)(grow + j) * N + gcol;
        if (OUT_BF16) ((short*)Cp)[off] = f2bf(acc[m][n][j]);
        else          ((float*)Cp)[off] = acc[m][n][j];
      }
    }
  }
}

// ---------------- 128x128 bf16 GEMM (kept for the small N=1024 GEMM) ----------------
template <int OUT_BF16>
__global__ __launch_bounds__(256) void gemm_bt(const short* __restrict__ A,
                                               const short* __restrict__ B,
                                               void* __restrict__ Cp,
                                               int M, int N, int K) {
  __shared__ short As[128 * 64];
  __shared__ short Bs[128 * 64];
  const int tid = threadIdx.x;
  const int wave = tid >> 6, lane = tid & 63;
  const int wr = wave >> 1, wc = wave & 1;
  const int row0 = blockIdx.y * 128, col0 = blockIdx.x * 128;
  const int lrow = lane & 15;
  const int kgrp = lane >> 4;

  f32x4 acc[4][4] = {};

  for (int k0 = 0; k0 < K; k0 += 64) {
#pragma unroll
    for (int it = 0; it < 4; ++it) {
      int idx = it * 256 + tid;
      int r = idx >> 3, c8 = (idx & 7) * 8;
      gload_lds16(A + (row0 + r) * K + k0 + c8, As + (it * 256 + wave * 64) * 8);
      gload_lds16(B + (col0 + r) * K + k0 + c8, Bs + (it * 256 + wave * 64) * 8);
    }
    __syncthreads();
#pragma unroll
    for (int kk = 0; kk < 2; ++kk) {
      bf16x8 a[4], b[4];
#pragma unroll
      for (int m = 0; m < 4; ++m)
        a[m] = *(const bf16x8*)(As + (wr * 64 + m * 16 + lrow) * 64 + kk * 32 + kgrp * 8);
#pragma unroll
      for (int n = 0; n < 4; ++n)
        b[n] = *(const bf16x8*)(Bs + (wc * 64 + n * 16 + lrow) * 64 + kk * 32 + kgrp * 8);
#pragma unroll
      for (int m = 0; m < 4; ++m)
#pragma unroll
        for (int n = 0; n < 4; ++n)
          acc[m][n] = MFMA_16x16x32(a[m], b[n], acc[m][n]);
    }
    __syncthreads();
  }

#pragma unroll
  for (int m = 0; m < 4; ++m) {
    int rbase = row0 + wr * 64 + m * 16 + kgrp * 4;
#pragma unroll
    for (int n = 0; n < 4; ++n) {
      int col = col0 + wc * 64 + n * 16 + lrow;
#pragma unroll
      for (int j = 0; j < 4; ++j) {
        int off = (rbase + j) * N + col;
        if (OUT_BF16) ((short*)Cp)[off] = f2bf(acc[m][n][j]);
        else          ((float*)Cp)[off] = acc[m][n][j];
      }
    }
  }
}

// ---------------- V transpose: vt[b,h,d,t] <- qkv[b,t, 2C + h*64 + d] ----------------
__global__ __launch_bounds__(256) void transpose_v(const short* __restrict__ qkv,
                                                   short* __restrict__ vt) {
  const int T = 2048;
  __shared__ short sm[64][72];
  const int bh = blockIdx.y, h = bh & 15, b = bh >> 4;
  const int t0 = blockIdx.x * 64;
  const int tid = threadIdx.x;
#pragma unroll
  for (int p = 0; p < 2; ++p) {
    int idx = p * 256 + tid;
    int tl = idx >> 3, d0 = (idx & 7) * 8;
    bf16x8 v = *(const bf16x8*)(qkv + (b * T + t0 + tl) * 3072 + 2048 + h * 64 + d0);
    *(bf16x8*)(&sm[tl][d0]) = v;
  }
  __syncthreads();
#pragma unroll
  for (int p = 0; p < 2; ++p) {
    int idx = p * 256 + tid;
    int d = idx >> 3, ts0 = (idx & 7) * 8;
    bf16x8 o;
#pragma unroll
    for (int j = 0; j < 8; ++j) o[j] = sm[ts0 + j][d];
    *(bf16x8*)(vt + (bh * 64 + d) * T + t0 + ts0) = o;
  }
}

// ---------------- fused attention ----------------
template <bool DIAG>
__device__ __forceinline__ void attn_step(
    const short* __restrict__ Kb, const short* __restrict__ Vb,
    short* __restrict__ Pw, const bf16x8 (&qf)[2], const float (&cbase)[4][4],
    float off, f32x4 (&acc)[4], float& den,
    int lrow, int kgrp, int l3, int dthr) {
  const float scale = 0.125f;
  f32x4 s[4];
#pragma unroll
  for (int r = 0; r < 4; ++r) {
    f32x4 z = {0.f, 0.f, 0.f, 0.f};
#pragma unroll
    for (int kk = 0; kk < 2; ++kk) {
      bf16x8 kf = *(const bf16x8*)(Kb + (r * 16 + lrow) * 64 + 8 * ((kk * 4 + kgrp) ^ l3));
      z = MFMA_16x16x32(kf, qf[kk], z);
    }
    s[r] = z;
  }
#pragma unroll
  for (int r = 0; r < 4; ++r) {
    float nm[4];
#pragma unroll
    for (int j = 0; j < 4; ++j) {
      float x = fmaf(s[r][j], scale, cbase[r][j] + off);
      if (DIAG) x = ((r * 16 + kgrp * 4 + j) > dthr) ? -10000.0f : x;
      float t = fmaf(x, x, 1.0f);
      float xr = x * __builtin_amdgcn_rsqf(t);
      float v = fmaf(xr, 0.5f, 0.5f);
      den += v;
      nm[j] = v;
    }
    u32x2 pk;
    pk[0] = cvt_pk_bf16(nm[0], nm[1]);
    pk[1] = cvt_pk_bf16(nm[2], nm[3]);
    *(u32x2*)(Pw + lrow * 64 + ((r * 16 + kgrp * 4) ^ (l3 * 8))) = pk;
  }
  asm volatile("s_waitcnt lgkmcnt(0)" ::: "memory");
#pragma unroll
  for (int kk = 0; kk < 2; ++kk) {
    bf16x8 pf = *(const bf16x8*)(Pw + lrow * 64 + 8 * ((kk * 4 + kgrp) ^ l3));
#pragma unroll
    for (int n = 0; n < 4; ++n) {
      bf16x8 vf = *(const bf16x8*)(Vb + (n * 16 + lrow) * 64 + 8 * ((kk * 4 + kgrp) ^ l3));
      acc[n] = MFMA_16x16x32(pf, vf, acc[n]);
    }
  }
}

// grid (16, B*H). Block bx handles q-tiles qiA=31-bx and qiB=bx (uniform 33 steps).
__global__ __launch_bounds__(256, 2) void attn_kernel(const short* __restrict__ qkv,
                                                      const short* __restrict__ vt,
                                                      const float* __restrict__ slopes,
                                                      short* __restrict__ attn_out) {
  const int T = 2048, C = 1024, C3 = 3072;
  __shared__ short Kl[2][4096];
  __shared__ short Vl[2][4096];
  __shared__ short Pl[4][2][1024];
  __shared__ float denl[4][16];

  const int tid = threadIdx.x, wave = tid >> 6, lane = tid & 63;
  const int bh = blockIdx.y, b = bh >> 4, h = bh & 15;
  const int bx = blockIdx.x;
  const int qiA = 31 - bx, qiB = bx;
  const int lrow = lane & 15, kgrp = lane >> 4, l3 = lrow & 7;
  const float slope = slopes[h];
  const int dthr = wave * 16 + lrow;

  const int qgA = qiA * 64 + wave * 16 + lrow;
  const int qgB = qiB * 64 + wave * 16 + lrow;
  bf16x8 qfA[2], qfB[2];
#pragma unroll
  for (int kk = 0; kk < 2; ++kk) {
    qfA[kk] = *(const bf16x8*)(qkv + (b * T + qgA) * C3 + h * 64 + kk * 32 + kgrp * 8);
    qfB[kk] = *(const bf16x8*)(qkv + (b * T + qgB) * C3 + h * 64 + kk * 32 + kgrp * 8);
  }

  float cbase[4][4];
#pragma unroll
  for (int r = 0; r < 4; ++r)
#pragma unroll
    for (int j = 0; j < 4; ++j)
      cbase[r][j] = slope * (float)(r * 16 + kgrp * 4 + j - wave * 16 - lrow);

  f32x4 accA[4] = {}, accB[4] = {};
  float denA = 0.f, denB = 0.f;

  auto STAGE = [&](int bufi, int kt) {
#pragma unroll
    for (int p = 0; p < 2; ++p) {
      int idx = p * 256 + tid;
      int r = idx >> 3;
      int c8s = ((idx & 7) ^ (r & 7)) * 8;
      gload_lds16(qkv + (b * T + kt * 64 + r) * C3 + C + h * 64 + c8s,
                  &Kl[bufi][(p * 256 + wave * 64) * 8]);
      gload_lds16(vt + (bh * 64 + r) * T + kt * 64 + c8s,
                  &Vl[bufi][(p * 256 + wave * 64) * 8]);
    }
  };

  STAGE(0, 0);
  __syncthreads();
  int cur = 0;
  int kt = 0;
  const float s64 = slope * 64.0f;

  for (; kt < qiB; ++kt) {
    STAGE(cur ^ 1, kt + 1);
    attn_step<false>(Kl[cur], Vl[cur], Pl[wave][0], qfA, cbase,
                     s64 * (float)(kt - qiA), accA, denA, lrow, kgrp, l3, dthr);
    attn_step<false>(Kl[cur], Vl[cur], Pl[wave][1], qfB, cbase,
                     s64 * (float)(kt - qiB), accB, denB, lrow, kgrp, l3, dthr);
    __syncthreads();
    cur ^= 1;
  }
  {
    STAGE(cur ^ 1, kt + 1);
    attn_step<false>(Kl[cur], Vl[cur], Pl[wave][0], qfA, cbase,
                     s64 * (float)(kt - qiA), accA, denA, lrow, kgrp, l3, dthr);
    attn_step<true>(Kl[cur], Vl[cur], Pl[wave][1], qfB, cbase,
                    0.0f, accB, denB, lrow, kgrp, l3, dthr);
    __syncthreads();
    cur ^= 1;
    ++kt;
  }
  for (; kt < qiA; ++kt) {
    STAGE(cur ^ 1, kt + 1);
    attn_step<false>(Kl[cur], Vl[cur], Pl[wave][0], qfA, cbase,
                     s64 * (float)(kt - qiA), accA, denA, lrow, kgrp, l3, dthr);
    __syncthreads();
    cur ^= 1;
  }
  attn_step<true>(Kl[cur], Vl[cur], Pl[wave][0], qfA, cbase,
                  0.0f, accA, denA, lrow, kgrp, l3, dthr);

  {
    float d2 = denA + __shfl_xor(denA, 16);
    d2 += __shfl_xor(d2, 32);
    denl[wave][lrow] = d2;
    float rcpd[4];
#pragma unroll
    for (int j = 0; j < 4; ++j)
      rcpd[j] = __builtin_amdgcn_rcpf(denl[wave][kgrp * 4 + j] + 1e-6f);
#pragma unroll
    for (int n = 0; n < 4; ++n)
#pragma unroll
      for (int j = 0; j < 4; ++j) {
        int qrow = kgrp * 4 + j;
        attn_out[(b * T + qiA * 64 + wave * 16 + qrow) * C + h * 64 + n * 16 + lrow] =
            f2bf(accA[n][j] * rcpd[j]);
      }
  }
  {
    float d2 = denB + __shfl_xor(denB, 16);
    d2 += __shfl_xor(d2, 32);
    denl[wave][lrow] = d2;
    float rcpd[4];
#pragma unroll
    for (int j = 0; j < 4; ++j)
      rcpd[j] = __builtin_amdgcn_rcpf(denl[wave][kgrp * 4 + j] + 1e-6f);
#pragma unroll
    for (int n = 0; n < 4; ++n)
#pragma unroll
      for (int j = 0; j < 4; ++j) {
        int qrow = kgrp * 4 + j;
        attn_out[(b * T + qiB * 64 + wave * 16 + qrow) * C + h * 64 + n * 16 + lrow] =
            f2bf(accB[n][j] * rcpd[j]);
      }
  }
}

// ---------------- launcher ----------------
extern "C" void kernel_launch(void* const* d_in, const int* in_sizes, int n_in,
                              void* d_out, int out_size, void* d_ws, size_t ws_size,
                              hipStream_t stream) {
  const float* x      = (const float*)d_in[0];
  const float* w_qkv  = (const float*)d_in[1];
  const float* w_out  = (const float*)d_in[2];
  const float* slopes = (const float*)d_in[3];

  const int B = 2, T = 2048, C = 1024;
  const int M = B * T;        // 4096
  const int N1 = 3 * C;       // 3072

  char* ws = (char*)d_ws;
  short* x_bf    = (short*)(ws);
  short* wqkv_bf = (short*)(ws + 8388608);
  short* wout_bf = (short*)(ws + 14680064);
  short* qkv_bf  = (short*)(ws + 16777216);
  short* vt_bf   = (short*)(ws + 41943040);
  short* ao_bf   = (short*)(ws + 50331648);

  cast_f32_bf16<<<(M * C / 8 + 255) / 256, 256, 0, stream>>>(x, x_bf, M * C / 8);
  cast_f32_bf16<<<(N1 * C / 8 + 255) / 256, 256, 0, stream>>>(w_qkv, wqkv_bf, N1 * C / 8);
  cast_f32_bf16<<<(C * C / 8 + 255) / 256, 256, 0, stream>>>(w_out, wout_bf, C * C / 8);

  // qkv = x @ w_qkv^T : 256^2 8-phase kernel, grid 16*12 = 192 (nwg%8==0)
  gemm256<1><<<dim3((M / 256) * (N1 / 256)), 512, 0, stream>>>(x_bf, wqkv_bf, qkv_bf,
                                                               M, N1, C, N1 / 256);

  transpose_v<<<dim3(T / 64, 32), 256, 0, stream>>>(qkv_bf, vt_bf);

  attn_kernel<<<dim3(16, 32), 256, 0, stream>>>(qkv_bf, vt_bf, slopes, ao_bf);

  gemm_bt<0><<<dim3(C / 128, M / 128), 256, 0, stream>>>(ao_bf, wout_bf, (float*)d_out, M, C, C);
}